// Round 3
// baseline (229.976 us; speedup 1.0000x reference)
//
#include <hip/hip_runtime.h>
#include <stdint.h>

// ---------------- problem constants ----------------
#define N_TOK 8192      // B*S = 4*2048
#define DIM   512       // D
#define HID   1024      // H
#define NE    8         // experts
#define NSLOT 16384     // N_TOK * K (K=2)
#define MAXSLOT 18432   // padded slots (<= 71*256 = 18176, rounded up)

typedef __attribute__((ext_vector_type(8))) short short8;   // 8 x bf16 (4 VGPRs)
typedef __attribute__((ext_vector_type(4))) float f32x4;    // MFMA C/D frag

// ---------------- workspace layout (bytes) ----------------
#define W1T_OFF  0ull                 // 8 MB
#define W2T_OFF  8388608ull           // 8 MB
#define H_OFF    16777216ull          // 18432*1024*2 = 37748736 -> end 54525952
#define Y_OFF    54525952ull          // 18432*512*2  = 18874368 -> end 73400320
#define XBF_OFF  54525952ull          // alias of Y (xbf dead before gemm2 writes y)
#define TOPI_OFF 73400320ull
#define TOPW_OFF 73465856ull
#define SLOT_OFF 73531392ull
#define ROWS_OFF 73596928ull
#define RW_OFF   73670656ull
#define CNT_OFF  73744384ull

__device__ __forceinline__ unsigned int f2bfu(float f) {
  union { float f; unsigned int i; } v; v.f = f;
  unsigned int u = v.i;
  return (u + 0x7FFFu + ((u >> 16) & 1u)) >> 16;  // RNE, bf16 bits in low 16
}
__device__ __forceinline__ float bf2f(unsigned int u) {
  union { unsigned int i; float f; } v; v.i = (u & 0xFFFFu) << 16; return v.f;
}
// fast GELU: x*sigmoid(1.5957691*x*(1+0.044715*x^2)); max |err| vs erf-GELU ~3e-4
__device__ __forceinline__ float gelu_f(float x) {
  float x2 = x * x;
  float u = x * (1.59576912f + 0.07135481f * x2);
  float ez = __expf(-u);
  return x * __builtin_amdgcn_rcpf(1.0f + ez);
}
// async global->LDS, 16B/lane. LDS dest = wave-uniform base + lane*16.
__device__ __forceinline__ void async16(void* lds, const void* g) {
  __builtin_amdgcn_global_load_lds(
      (const __attribute__((address_space(1))) unsigned int*)g,
      (__attribute__((address_space(3))) unsigned int*)lds, 16, 0, 0);
}

// ================= 1. weight transpose + downcast =================
__global__ __launch_bounds__(256) void k_transpose(
    const float* __restrict__ w1, const float* __restrict__ w2,
    unsigned short* __restrict__ w1t, unsigned short* __restrict__ w2t) {
  __shared__ unsigned short tile[64][68];   // +4 pad breaks bank conflicts
  int b = blockIdx.x, tid = threadIdx.x;
  const float* src; unsigned short* dst; int R, C;
  if (b < 1024) { int e = b >> 7; int t = b & 127;
    src = w1 + (size_t)e * 524288; dst = w1t + (size_t)e * 524288; R = 512; C = 1024;
    int tr = t >> 4, tc = t & 15;  // 8 x 16 tiles of 64x64
    src += (size_t)tr * 64 * C + tc * 64; dst += (size_t)tc * 64 * R + tr * 64;
  } else { b -= 1024; int e = b >> 7; int t = b & 127;
    src = w2 + (size_t)e * 524288; dst = w2t + (size_t)e * 524288; R = 1024; C = 512;
    int tr = t >> 3, tc = t & 7;   // 16 x 8 tiles
    src += (size_t)tr * 64 * C + tc * 64; dst += (size_t)tc * 64 * R + tr * 64;
  }
#pragma unroll
  for (int i = 0; i < 4; ++i) {
    int l = i * 256 + tid;
    int r = l >> 4, c4 = (l & 15) << 2;
    float4 v = *(const float4*)(src + (size_t)r * C + c4);
    tile[r][c4 + 0] = (unsigned short)f2bfu(v.x);
    tile[r][c4 + 1] = (unsigned short)f2bfu(v.y);
    tile[r][c4 + 2] = (unsigned short)f2bfu(v.z);
    tile[r][c4 + 3] = (unsigned short)f2bfu(v.w);
  }
  __syncthreads();
#pragma unroll
  for (int i = 0; i < 2; ++i) {           // 16B stores: 512 chunks of 8
    int l = i * 256 + tid;
    int rr = l >> 3, c8 = (l & 7) << 3;
    ushort4 a, b2v;
    a.x = tile[c8 + 0][rr]; a.y = tile[c8 + 1][rr];
    a.z = tile[c8 + 2][rr]; a.w = tile[c8 + 3][rr];
    b2v.x = tile[c8 + 4][rr]; b2v.y = tile[c8 + 5][rr];
    b2v.z = tile[c8 + 6][rr]; b2v.w = tile[c8 + 7][rr];
    uint4 pk;
    pk.x = (unsigned int)a.x | ((unsigned int)a.y << 16);
    pk.y = (unsigned int)a.z | ((unsigned int)a.w << 16);
    pk.z = (unsigned int)b2v.x | ((unsigned int)b2v.y << 16);
    pk.w = (unsigned int)b2v.z | ((unsigned int)b2v.w << 16);
    *(uint4*)(dst + (size_t)rr * R + c8) = pk;
  }
}

// ================= 2. router: one wave per token; also emits xbf =================
__global__ __launch_bounds__(256) void k_router(
    const float* __restrict__ x, const float* __restrict__ gw,
    const float* __restrict__ gb, float* __restrict__ probs_out,
    int2* __restrict__ topi, float2* __restrict__ topw,
    unsigned short* __restrict__ xbf) {
  int wave = threadIdx.x >> 6, lane = threadIdx.x & 63;
  int n = blockIdx.x * 4 + wave;
  const float4* xr = (const float4*)(x + (size_t)n * DIM);
  float4 x0 = xr[lane * 2], x1 = xr[lane * 2 + 1];
  float xf[8] = {x0.x, x0.y, x0.z, x0.w, x1.x, x1.y, x1.z, x1.w};
  uint4 pa;
  pa.x = f2bfu(xf[0]) | (f2bfu(xf[1]) << 16);
  pa.y = f2bfu(xf[2]) | (f2bfu(xf[3]) << 16);
  pa.z = f2bfu(xf[4]) | (f2bfu(xf[5]) << 16);
  pa.w = f2bfu(xf[6]) | (f2bfu(xf[7]) << 16);
  *(uint4*)(xbf + (size_t)n * DIM + lane * 8) = pa;
  float acc[8] = {0.f,0.f,0.f,0.f,0.f,0.f,0.f,0.f};
  const float4* gwr = (const float4*)gw;
#pragma unroll
  for (int j = 0; j < 8; ++j) {
    int d = lane * 8 + j;
    float4 g0 = gwr[d * 2], g1 = gwr[d * 2 + 1];
    acc[0] += xf[j] * g0.x; acc[1] += xf[j] * g0.y; acc[2] += xf[j] * g0.z; acc[3] += xf[j] * g0.w;
    acc[4] += xf[j] * g1.x; acc[5] += xf[j] * g1.y; acc[6] += xf[j] * g1.z; acc[7] += xf[j] * g1.w;
  }
#pragma unroll
  for (int o = 1; o < 64; o <<= 1)
#pragma unroll
    for (int e = 0; e < 8; ++e) acc[e] += __shfl_xor(acc[e], o, 64);
  float p[8], mx = -1e30f, s = 0.f;
#pragma unroll
  for (int e = 0; e < 8; ++e) { p[e] = acc[e] + gb[e]; mx = fmaxf(mx, p[e]); }
#pragma unroll
  for (int e = 0; e < 8; ++e) { p[e] = __expf(p[e] - mx); s += p[e]; }
  float inv = 1.f / s;
#pragma unroll
  for (int e = 0; e < 8; ++e) p[e] *= inv;
  if (lane < 8) probs_out[(size_t)n * NE + lane] = p[lane];
  if (lane == 0) {
    int i0 = 0; float v0 = p[0];
#pragma unroll
    for (int e = 1; e < 8; ++e) if (p[e] > v0) { v0 = p[e]; i0 = e; }   // first-max (jax tie rule)
    int i1 = -1; float v1 = -1.f;
#pragma unroll
    for (int e = 0; e < 8; ++e) if (e != i0 && p[e] > v1) { v1 = p[e]; i1 = e; }
    float sw = 1.f / (v0 + v1);
    topi[n] = make_int2(i0, i1);
    topw[n] = make_float2(v0 * sw, v1 * sw);
  }
}

// ================= 3. count: histogram + 256-padded scan + tile map + pad fill =================
__global__ __launch_bounds__(1024) void k_count(
    const int2* __restrict__ topi, int* __restrict__ meta, int* __restrict__ chunk_base,
    int* __restrict__ rows, float* __restrict__ rw) {
  __shared__ int ch[32][8];
  __shared__ int tot[8], poff_s[9], tiles_s[8];
  int t = threadIdx.x;
  int g = t >> 5;
  if (t < 256) ((int*)ch)[t] = 0;
  __syncthreads();
  int c[8] = {0,0,0,0,0,0,0,0};
  int base_tok = t * 8;
#pragma unroll
  for (int i = 0; i < 8; ++i) {
    int2 e = topi[base_tok + i];
#pragma unroll
    for (int k = 0; k < 8; ++k) c[k] += (e.x == k) + (e.y == k);
  }
#pragma unroll
  for (int k = 0; k < 8; ++k) if (c[k]) atomicAdd(&ch[g][k], c[k]);
  __syncthreads();
  if (t < 8) {
    int a = 0;
#pragma unroll
    for (int b = 0; b < 32; ++b) { int v = ch[b][t]; ch[b][t] = a; a += v; }
    tot[t] = a; meta[t] = a;
  }
  __syncthreads();
  if (t == 0) {
    int a = 0, ts = 0;
#pragma unroll
    for (int e = 0; e < 8; ++e) {
      int tiles = (tot[e] + 255) >> 8;          // 256-row tiles now
      poff_s[e] = a; tiles_s[e] = tiles;
      meta[16 + e] = a; meta[32 + e] = ts;
      a += tiles << 8; ts += tiles;
    }
    poff_s[8] = a; meta[24] = a; meta[40] = ts;
  }
  __syncthreads();
  if (t < 256) {
    int b = t >> 3, e = t & 7;
    chunk_base[t] = poff_s[e] + ch[b][e];
  }
#pragma unroll
  for (int e = 0; e < 8; ++e) {
    int padn = (tiles_s[e] << 8) - tot[e];      // up to 255 pad rows
    if (t < padn) {
      int s = poff_s[e] + tot[e] + t;
      rows[s] = 0; rw[s] = 0.f;
    }
  }
}

// ================= 4. slot assignment: LDS atomics only =================
__global__ __launch_bounds__(256) void k_assign(
    const int2* __restrict__ topi, const float2* __restrict__ topw,
    const int* __restrict__ chunk_base,
    int* __restrict__ rows, float* __restrict__ rw, int* __restrict__ slot_of) {
  __shared__ int lcnt[8];
  __shared__ int lbase[8];
  int t = threadIdx.x, b = blockIdx.x;
  if (t < 8) { lcnt[t] = 0; lbase[t] = chunk_base[b * 8 + t]; }
  __syncthreads();
  int n = b * 256 + t;
  int2 ei = topi[n]; float2 wv = topw[n];
  int r0 = atomicAdd(&lcnt[ei.x], 1);
  int r1 = atomicAdd(&lcnt[ei.y], 1);
  int s0 = lbase[ei.x] + r0;
  int s1 = lbase[ei.y] + r1;
  rows[s0] = n; rw[s0] = wv.x; slot_of[2 * n] = s0;
  rows[s1] = n; rw[s1] = wv.y; slot_of[2 * n + 1] = s1;
}

// ================= 5. GEMM1: h = gelu(gather(xbf) @ w1 + b1), h bf16 =================
// Phase-split schedule (T3+T4+T5): BM=256 x BN=128, 8 waves (4M x 2N, each 64x64).
// One phase per K=32 subtile. 5-buffer rotation (A 16KB + B 8KB per buf = 120KB
// LDS, 1 block/CU, 2 waves/SIMD). Per phase: stage 3 loads for tile t+3 ->
// 8 ds_read_b128 -> setprio(1) 16 MFMA setprio(0) -> vmcnt(6) -> s_barrier.
// vmcnt(6) forces tile t+1 landed (FIFO) while t+2/t+3's 6 loads stay in
// flight -- never drains to 0 in the main loop. Buffer (t+3)%5 was last read
// at phase t-2 (two barriers back) -> race-free.
// Swizzle (verified, 0 conflicts): chunk (r,c) at LDS slot r*4 + (c^((r>>1)&3)).
__global__ __launch_bounds__(512, 2) void k_gemm1(
    const unsigned short* __restrict__ xbf, const unsigned short* __restrict__ w1t,
    const float* __restrict__ b1, const int* __restrict__ meta,
    const int* __restrict__ rows, unsigned short* __restrict__ h) {
  int t = blockIdx.y;
  if (t >= meta[40]) return;
  int e = 0;
#pragma unroll
  for (int i = 1; i < 8; ++i) if (t >= meta[32 + i]) e = i;
  int mt = t - meta[32 + e];
  int row0 = meta[16 + e] + (mt << 8);
  int nt = blockIdx.x;
  __shared__ __align__(16) unsigned short As[5][8192];   // 256 rows x 32 K, swizzled chunks
  __shared__ __align__(16) unsigned short Bs[5][4096];   // 128 rows x 32 K
  int tid = threadIdx.x;
  int wave = tid >> 6, lane = tid & 63;
  int wr = wave & 3, wc = wave >> 2;                     // 4M x 2N wave grid
  f32x4 acc[4][4] = {};                                  // acc[an][am]
  const unsigned short* bBase = w1t + (size_t)e * HID * DIM + (size_t)(nt * 128) * DIM;

  // K-invariant staging bases. A: 1024 chunks (256 rows x 4), inst j covers
  // chunk s = j*512 + tid; B: 512 chunks, s = tid. Source col pre-inverse-swizzled.
  const unsigned short *ga0, *ga1, *gbp;
  {
    int s0 = tid;        int r0g = s0 >> 2; int c0 = ((s0 & 3) ^ ((r0g >> 1) & 3)) << 3;
    ga0 = xbf + (size_t)rows[row0 + r0g] * DIM + c0;
    int s1 = 512 + tid;  int r1g = s1 >> 2; int c1 = ((s1 & 3) ^ ((r1g >> 1) & 3)) << 3;
    ga1 = xbf + (size_t)rows[row0 + r1g] * DIM + c1;
    int sb = tid;        int rbg = sb >> 2; int cb = ((sb & 3) ^ ((rbg >> 1) & 3)) << 3;
    gbp = bBase + (size_t)rbg * DIM + cb;
  }
  int la0 = (wave * 64) * 8;          // LDS elem base, inst 0 (lane*16B implicit)
  int la1 = (512 + wave * 64) * 8;    // inst 1
  int lb  = (wave * 64) * 8;

#define STAGE1(buf, kt) do { \
    async16(&As[buf][la0], ga0 + (kt) * 32); \
    async16(&As[buf][la1], ga1 + (kt) * 32); \
    async16(&Bs[buf][lb],  gbp + (kt) * 32); \
  } while (0)

  // prologue: 3 tiles in flight, wait only for tile 0 (6 newer stay in flight)
  STAGE1(0, 0); STAGE1(1, 1); STAGE1(2, 2);
  asm volatile("s_waitcnt vmcnt(6)" ::: "memory");
  __builtin_amdgcn_s_barrier();

  int ml = lane & 15, q = lane >> 4;
  int offA[4], offB[4];               // phase-invariant swizzled chunk offsets (elems)
#pragma unroll
  for (int am = 0; am < 4; ++am) { int ra = wr * 64 + am * 16 + ml; offA[am] = (ra * 4 + (q ^ ((ra >> 1) & 3))) * 8; }
#pragma unroll
  for (int an = 0; an < 4; ++an) { int rb = wc * 64 + an * 16 + ml; offB[an] = (rb * 4 + (q ^ ((rb >> 1) & 3))) * 8; }

#pragma unroll
  for (int kt = 0; kt < 16; ++kt) {
    int buf = kt % 5;
    if (kt + 3 < 16) STAGE1((kt + 3) % 5, kt + 3);
    short8 tf[4], wf[4];
#pragma unroll
    for (int am = 0; am < 4; ++am) tf[am] = *(const short8*)&As[buf][offA[am]];
#pragma unroll
    for (int an = 0; an < 4; ++an) wf[an] = *(const short8*)&Bs[buf][offB[an]];
    __builtin_amdgcn_s_setprio(1);
#pragma unroll
    for (int an = 0; an < 4; ++an)
#pragma unroll
      for (int am = 0; am < 4; ++am)
        acc[an][am] = __builtin_amdgcn_mfma_f32_16x16x32_bf16(wf[an], tf[am], acc[an][am], 0, 0, 0);
    __builtin_amdgcn_s_setprio(0);
    if (kt < 15) {
      if (kt <= 12)      asm volatile("s_waitcnt vmcnt(6)" ::: "memory");
      else if (kt == 13) asm volatile("s_waitcnt vmcnt(3)" ::: "memory");
      else               asm volatile("s_waitcnt vmcnt(0)" ::: "memory");
      __builtin_amdgcn_s_barrier();
    }
  }
#undef STAGE1

  // epilogue: lane holds token row (lane&15) x 4 consecutive cols (quad*4..+3)
#pragma unroll
  for (int am = 0; am < 4; ++am) {
    int slot_r = row0 + wr * 64 + am * 16 + ml;
    unsigned short* hrow = h + (size_t)slot_r * HID;
#pragma unroll
    for (int an = 0; an < 4; ++an) {
      int colb = nt * 128 + wc * 64 + an * 16 + q * 4;
      float4 bias = *(const float4*)&b1[e * HID + colb];
      f32x4 v = acc[an][am];
      float g0 = gelu_f(v[0] + bias.x);
      float g1 = gelu_f(v[1] + bias.y);
      float g2 = gelu_f(v[2] + bias.z);
      float g3 = gelu_f(v[3] + bias.w);
      uint2 pk;
      pk.x = f2bfu(g0) | (f2bfu(g1) << 16);
      pk.y = f2bfu(g2) | (f2bfu(g3) << 16);
      *(uint2*)(hrow + colb) = pk;
    }
  }
}

// ================= 6. GEMM2: y = (h @ w2 + b2) * weight, y bf16 =================
// Same phase-split structure, K = 1024 -> 32 phases. grid (4, 71).
__global__ __launch_bounds__(512, 2) void k_gemm2(
    const unsigned short* __restrict__ h, const unsigned short* __restrict__ w2t,
    const float* __restrict__ b2, const int* __restrict__ meta,
    const float* __restrict__ rw, unsigned short* __restrict__ y) {
  int t = blockIdx.y;
  if (t >= meta[40]) return;
  int e = 0;
#pragma unroll
  for (int i = 1; i < 8; ++i) if (t >= meta[32 + i]) e = i;
  int mt = t - meta[32 + e];
  int row0 = meta[16 + e] + (mt << 8);
  int nt = blockIdx.x;
  __shared__ __align__(16) unsigned short As[5][8192];
  __shared__ __align__(16) unsigned short Bs[5][4096];
  int tid = threadIdx.x;
  int wave = tid >> 6, lane = tid & 63;
  int wr = wave & 3, wc = wave >> 2;
  f32x4 acc[4][4] = {};
  const unsigned short* aBase = h + (size_t)row0 * HID;
  const unsigned short* bBase = w2t + (size_t)e * DIM * HID + (size_t)(nt * 128) * HID;

  const unsigned short *ga0, *ga1, *gbp;
  {
    int s0 = tid;        int r0g = s0 >> 2; int c0 = ((s0 & 3) ^ ((r0g >> 1) & 3)) << 3;
    ga0 = aBase + (size_t)r0g * HID + c0;
    int s1 = 512 + tid;  int r1g = s1 >> 2; int c1 = ((s1 & 3) ^ ((r1g >> 1) & 3)) << 3;
    ga1 = aBase + (size_t)r1g * HID + c1;
    int sb = tid;        int rbg = sb >> 2; int cb = ((sb & 3) ^ ((rbg >> 1) & 3)) << 3;
    gbp = bBase + (size_t)rbg * HID + cb;
  }
  int la0 = (wave * 64) * 8;
  int la1 = (512 + wave * 64) * 8;
  int lb  = (wave * 64) * 8;

#define STAGE2(buf, kt) do { \
    async16(&As[buf][la0], ga0 + (kt) * 32); \
    async16(&As[buf][la1], ga1 + (kt) * 32); \
    async16(&Bs[buf][lb],  gbp + (kt) * 32); \
  } while (0)

  STAGE2(0, 0); STAGE2(1, 1); STAGE2(2, 2);
  asm volatile("s_waitcnt vmcnt(6)" ::: "memory");
  __builtin_amdgcn_s_barrier();

  int ml = lane & 15, q = lane >> 4;
  int offA[4], offB[4];
#pragma unroll
  for (int am = 0; am < 4; ++am) { int ra = wr * 64 + am * 16 + ml; offA[am] = (ra * 4 + (q ^ ((ra >> 1) & 3))) * 8; }
#pragma unroll
  for (int an = 0; an < 4; ++an) { int rb = wc * 64 + an * 16 + ml; offB[an] = (rb * 4 + (q ^ ((rb >> 1) & 3))) * 8; }

#pragma unroll
  for (int kt = 0; kt < 32; ++kt) {
    int buf = kt % 5;
    if (kt + 3 < 32) STAGE2((kt + 3) % 5, kt + 3);
    short8 tf[4], wf[4];
#pragma unroll
    for (int am = 0; am < 4; ++am) tf[am] = *(const short8*)&As[buf][offA[am]];
#pragma unroll
    for (int an = 0; an < 4; ++an) wf[an] = *(const short8*)&Bs[buf][offB[an]];
    __builtin_amdgcn_s_setprio(1);
#pragma unroll
    for (int an = 0; an < 4; ++an)
#pragma unroll
      for (int am = 0; am < 4; ++am)
        acc[an][am] = __builtin_amdgcn_mfma_f32_16x16x32_bf16(wf[an], tf[am], acc[an][am], 0, 0, 0);
    __builtin_amdgcn_s_setprio(0);
    if (kt < 31) {
      if (kt <= 28)      asm volatile("s_waitcnt vmcnt(6)" ::: "memory");
      else if (kt == 29) asm volatile("s_waitcnt vmcnt(3)" ::: "memory");
      else               asm volatile("s_waitcnt vmcnt(0)" ::: "memory");
      __builtin_amdgcn_s_barrier();
    }
  }
#undef STAGE2

#pragma unroll
  for (int am = 0; am < 4; ++am) {
    int slot_r = row0 + wr * 64 + am * 16 + ml;
    float w = rw[slot_r];
    unsigned short* yrow = y + (size_t)slot_r * DIM;
#pragma unroll
    for (int an = 0; an < 4; ++an) {
      int colb = nt * 128 + wc * 64 + an * 16 + q * 4;
      float4 bias = *(const float4*)&b2[e * DIM + colb];
      f32x4 v = acc[an][am];
      uint2 pk;
      pk.x = f2bfu((v[0] + bias.x) * w) | (f2bfu((v[1] + bias.y) * w) << 16);
      pk.y = f2bfu((v[2] + bias.z) * w) | (f2bfu((v[3] + bias.w) * w) << 16);
      *(uint2*)(yrow + colb) = pk;
    }
  }
}

// ================= 7. combine: out[n] = y[slot0] + y[slot1] (bf16 -> fp32) =================
__global__ __launch_bounds__(256) void k_combine(
    const unsigned short* __restrict__ y, const int* __restrict__ slot_of,
    float* __restrict__ out) {
  int t = blockIdx.x * 256 + threadIdx.x;
  int n = t >> 6, c = (t & 63) << 3;
  int s0 = slot_of[2 * n], s1 = slot_of[2 * n + 1];
  uint4 u0 = *(const uint4*)(y + (size_t)s0 * DIM + c);
  uint4 u1 = *(const uint4*)(y + (size_t)s1 * DIM + c);
  float4 o0, o1;
  o0.x = bf2f(u0.x) + bf2f(u1.x); o0.y = bf2f(u0.x >> 16) + bf2f(u1.x >> 16);
  o0.z = bf2f(u0.y) + bf2f(u1.y); o0.w = bf2f(u0.y >> 16) + bf2f(u1.y >> 16);
  o1.x = bf2f(u0.z) + bf2f(u1.z); o1.y = bf2f(u0.z >> 16) + bf2f(u1.z >> 16);
  o1.z = bf2f(u0.w) + bf2f(u1.w); o1.w = bf2f(u0.w >> 16) + bf2f(u1.w >> 16);
  *(float4*)(out + (size_t)n * DIM + c) = o0;
  *(float4*)(out + (size_t)n * DIM + c + 4) = o1;
}

// ================= launch =================
extern "C" void kernel_launch(void* const* d_in, const int* in_sizes, int n_in,
                              void* d_out, int out_size, void* d_ws, size_t ws_size,
                              hipStream_t stream) {
  const float* x  = (const float*)d_in[0];
  const float* gw = (const float*)d_in[1];
  const float* gb = (const float*)d_in[2];
  const float* w1 = (const float*)d_in[3];
  const float* b1 = (const float*)d_in[4];
  const float* w2 = (const float*)d_in[5];
  const float* b2 = (const float*)d_in[6];
  float* out = (float*)d_out;
  char* ws = (char*)d_ws;

  unsigned short* w1t = (unsigned short*)(ws + W1T_OFF);
  unsigned short* w2t = (unsigned short*)(ws + W2T_OFF);
  unsigned short* h   = (unsigned short*)(ws + H_OFF);
  unsigned short* y   = (unsigned short*)(ws + Y_OFF);
  unsigned short* xbf = (unsigned short*)(ws + XBF_OFF);
  int2*   topi    = (int2*)(ws + TOPI_OFF);
  float2* topw    = (float2*)(ws + TOPW_OFF);
  int*    slot_of = (int*)(ws + SLOT_OFF);
  int*    rows    = (int*)(ws + ROWS_OFF);
  float*  rw      = (float*)(ws + RW_OFF);
  int*    meta    = (int*)(ws + CNT_OFF);
  int*    chunk_base = meta + 64;
  float*  probs   = out + (size_t)N_TOK * DIM;

  k_transpose<<<dim3(2048), dim3(256), 0, stream>>>(w1, w2, w1t, w2t);
  k_router   <<<dim3(2048), dim3(256), 0, stream>>>(x, gw, gb, probs, topi, topw, xbf);
  k_count    <<<dim3(1),    dim3(1024), 0, stream>>>(topi, meta, chunk_base, rows, rw);
  k_assign   <<<dim3(32),   dim3(256), 0, stream>>>(topi, topw, chunk_base, rows, rw, slot_of);
  k_gemm1    <<<dim3(8, 71), dim3(512), 0, stream>>>(xbf, w1t, b1, meta, rows, h);
  k_gemm2    <<<dim3(4, 71), dim3(512), 0, stream>>>(h, w2t, b2, meta, rw, y);
  k_combine  <<<dim3(2048), dim3(256), 0, stream>>>(y, slot_of, out);
}

// Round 4
// 207.197 us; speedup vs baseline: 1.1099x; 1.1099x over previous
//
#include <hip/hip_runtime.h>
#include <stdint.h>

// ---------------- problem constants ----------------
#define N_TOK 8192      // B*S = 4*2048
#define DIM   512       // D
#define HID   1024      // H
#define NE    8         // experts
#define NSLOT 16384     // N_TOK * K (K=2)
#define MAXSLOT 17408   // padded slots (<= 136*128)

typedef __attribute__((ext_vector_type(8))) short short8;   // 8 x bf16 (4 VGPRs)
typedef __attribute__((ext_vector_type(4))) float f32x4;    // MFMA C/D frag

// ---------------- workspace layout (bytes) ----------------
#define W1T_OFF  0ull
#define W2T_OFF  8388608ull
#define H_OFF    16777216ull          // 17408*1024*2 = 35651584
#define Y_OFF    52428800ull          // 17408*512*2  = 17825792
#define XBF_OFF  52428800ull          // alias of Y (xbf dead before gemm2 writes y)
#define TOPI_OFF 70254592ull
#define TOPW_OFF 70320128ull
#define SLOT_OFF 70385664ull
#define ROWS_OFF 70451200ull
#define RW_OFF   70520832ull
#define CNT_OFF  70590464ull

__device__ __forceinline__ unsigned int f2bfu(float f) {
  union { float f; unsigned int i; } v; v.f = f;
  unsigned int u = v.i;
  return (u + 0x7FFFu + ((u >> 16) & 1u)) >> 16;  // RNE, bf16 bits in low 16
}
__device__ __forceinline__ float bf2f(unsigned int u) {
  union { unsigned int i; float f; } v; v.i = (u & 0xFFFFu) << 16; return v.f;
}
// fast GELU: x*sigmoid(1.5957691*x*(1+0.044715*x^2)); max |err| vs erf-GELU ~3e-4
__device__ __forceinline__ float gelu_f(float x) {
  float x2 = x * x;
  float u = x * (1.59576912f + 0.07135481f * x2);
  float ez = __expf(-u);
  return x * __builtin_amdgcn_rcpf(1.0f + ez);
}
// async global->LDS, 16B/lane. LDS dest = wave-uniform base + lane*16.
__device__ __forceinline__ void async16(void* lds, const void* g) {
  __builtin_amdgcn_global_load_lds(
      (const __attribute__((address_space(1))) unsigned int*)g,
      (__attribute__((address_space(3))) unsigned int*)lds, 16, 0, 0);
}

// ================= 1. prep: weight transpose+downcast (blocks 0..2047)
//                            + router (blocks 2048..4095) =================
__global__ __launch_bounds__(256) void k_prep(
    const float* __restrict__ w1, const float* __restrict__ w2,
    unsigned short* __restrict__ w1t, unsigned short* __restrict__ w2t,
    const float* __restrict__ x, const float* __restrict__ gw,
    const float* __restrict__ gb, float* __restrict__ probs_out,
    int2* __restrict__ topi, float2* __restrict__ topw,
    unsigned short* __restrict__ xbf) {
  __shared__ unsigned short tile[64][68];   // transpose path only; +4 pad
  int tid = threadIdx.x;
  if (blockIdx.x < 2048) {
    // ---- transpose path ----
    int b = blockIdx.x;
    const float* src; unsigned short* dst; int R, C;
    if (b < 1024) { int e = b >> 7; int t = b & 127;
      src = w1 + (size_t)e * 524288; dst = w1t + (size_t)e * 524288; R = 512; C = 1024;
      int tr = t >> 4, tc = t & 15;  // 8 x 16 tiles of 64x64
      src += (size_t)tr * 64 * C + tc * 64; dst += (size_t)tc * 64 * R + tr * 64;
    } else { b -= 1024; int e = b >> 7; int t = b & 127;
      src = w2 + (size_t)e * 524288; dst = w2t + (size_t)e * 524288; R = 1024; C = 512;
      int tr = t >> 3, tc = t & 7;   // 16 x 8 tiles
      src += (size_t)tr * 64 * C + tc * 64; dst += (size_t)tc * 64 * R + tr * 64;
    }
#pragma unroll
    for (int i = 0; i < 4; ++i) {
      int l = i * 256 + tid;
      int r = l >> 4, c4 = (l & 15) << 2;
      float4 v = *(const float4*)(src + (size_t)r * C + c4);
      tile[r][c4 + 0] = (unsigned short)f2bfu(v.x);
      tile[r][c4 + 1] = (unsigned short)f2bfu(v.y);
      tile[r][c4 + 2] = (unsigned short)f2bfu(v.z);
      tile[r][c4 + 3] = (unsigned short)f2bfu(v.w);
    }
    __syncthreads();
#pragma unroll
    for (int i = 0; i < 2; ++i) {           // 16B stores: 512 chunks of 8
      int l = i * 256 + tid;
      int rr = l >> 3, c8 = (l & 7) << 3;
      ushort4 a, b2v;
      a.x = tile[c8 + 0][rr]; a.y = tile[c8 + 1][rr];
      a.z = tile[c8 + 2][rr]; a.w = tile[c8 + 3][rr];
      b2v.x = tile[c8 + 4][rr]; b2v.y = tile[c8 + 5][rr];
      b2v.z = tile[c8 + 6][rr]; b2v.w = tile[c8 + 7][rr];
      uint4 pk;
      pk.x = (unsigned int)a.x | ((unsigned int)a.y << 16);
      pk.y = (unsigned int)a.z | ((unsigned int)a.w << 16);
      pk.z = (unsigned int)b2v.x | ((unsigned int)b2v.y << 16);
      pk.w = (unsigned int)b2v.z | ((unsigned int)b2v.w << 16);
      *(uint4*)(dst + (size_t)rr * R + c8) = pk;
    }
  } else {
    // ---- router path: one wave per token; also emits xbf ----
    int wave = tid >> 6, lane = tid & 63;
    int n = (blockIdx.x - 2048) * 4 + wave;
    const float4* xr = (const float4*)(x + (size_t)n * DIM);
    float4 x0 = xr[lane * 2], x1 = xr[lane * 2 + 1];
    float xf[8] = {x0.x, x0.y, x0.z, x0.w, x1.x, x1.y, x1.z, x1.w};
    uint4 pa;
    pa.x = f2bfu(xf[0]) | (f2bfu(xf[1]) << 16);
    pa.y = f2bfu(xf[2]) | (f2bfu(xf[3]) << 16);
    pa.z = f2bfu(xf[4]) | (f2bfu(xf[5]) << 16);
    pa.w = f2bfu(xf[6]) | (f2bfu(xf[7]) << 16);
    *(uint4*)(xbf + (size_t)n * DIM + lane * 8) = pa;
    float acc[8] = {0.f,0.f,0.f,0.f,0.f,0.f,0.f,0.f};
    const float4* gwr = (const float4*)gw;
#pragma unroll
    for (int j = 0; j < 8; ++j) {
      int d = lane * 8 + j;
      float4 g0 = gwr[d * 2], g1 = gwr[d * 2 + 1];
      acc[0] += xf[j] * g0.x; acc[1] += xf[j] * g0.y; acc[2] += xf[j] * g0.z; acc[3] += xf[j] * g0.w;
      acc[4] += xf[j] * g1.x; acc[5] += xf[j] * g1.y; acc[6] += xf[j] * g1.z; acc[7] += xf[j] * g1.w;
    }
#pragma unroll
    for (int o = 1; o < 64; o <<= 1)
#pragma unroll
      for (int e = 0; e < 8; ++e) acc[e] += __shfl_xor(acc[e], o, 64);
    float p[8], mx = -1e30f, s = 0.f;
#pragma unroll
    for (int e = 0; e < 8; ++e) { p[e] = acc[e] + gb[e]; mx = fmaxf(mx, p[e]); }
#pragma unroll
    for (int e = 0; e < 8; ++e) { p[e] = __expf(p[e] - mx); s += p[e]; }
    float inv = 1.f / s;
#pragma unroll
    for (int e = 0; e < 8; ++e) p[e] *= inv;
    if (lane < 8) probs_out[(size_t)n * NE + lane] = p[lane];
    if (lane == 0) {
      int i0 = 0; float v0 = p[0];
#pragma unroll
      for (int e = 1; e < 8; ++e) if (p[e] > v0) { v0 = p[e]; i0 = e; }   // first-max (jax tie rule)
      int i1 = -1; float v1 = -1.f;
#pragma unroll
      for (int e = 0; e < 8; ++e) if (e != i0 && p[e] > v1) { v1 = p[e]; i1 = e; }
      float sw = 1.f / (v0 + v1);
      topi[n] = make_int2(i0, i1);
      topw[n] = make_float2(v0 * sw, v1 * sw);
    }
  }
}

// ================= 2. count+assign fused: histogram + padded scan + slot
// assignment via shfl prefix-scan (no second kernel, no global atomics) =====
__global__ __launch_bounds__(1024) void k_countassign(
    const int2* __restrict__ topi, const float2* __restrict__ topw,
    int* __restrict__ meta, int* __restrict__ rows, float* __restrict__ rw,
    int* __restrict__ slot_of) {
  __shared__ int ch[32][8];                // chunk histograms -> exclusive bases
  __shared__ int tot[8], poff_s[9], tiles_s[8];
  __shared__ int sm_off[1024 * 8];         // per-thread per-expert running offset (32 KB)
  int t = threadIdx.x, g = t >> 5;         // chunk = 256 tokens = 32 threads
  if (t < 256) ((int*)ch)[t] = 0;
  __syncthreads();
  int2 te[8]; float2 tw[8];
  int c[8] = {0,0,0,0,0,0,0,0};
  int base_tok = t * 8;
#pragma unroll
  for (int i = 0; i < 8; ++i) {
    te[i] = topi[base_tok + i];
    tw[i] = topw[base_tok + i];
#pragma unroll
    for (int k = 0; k < 8; ++k) c[k] += (te[i].x == k) + (te[i].y == k);
  }
#pragma unroll
  for (int k = 0; k < 8; ++k) if (c[k]) atomicAdd(&ch[g][k], c[k]);
  // exclusive prefix over the 32 threads of this chunk, per expert (width-32 segments)
#pragma unroll
  for (int k = 0; k < 8; ++k) {
    int s = c[k];
#pragma unroll
    for (int d = 1; d < 32; d <<= 1) {
      int u = __shfl_up(s, d, 32);
      if ((t & 31) >= d) s += u;
    }
    sm_off[t * 8 + k] = s - c[k];          // exclusive within-chunk offset
  }
  __syncthreads();
  if (t < 8) {
    int a = 0;
#pragma unroll
    for (int b = 0; b < 32; ++b) { int v = ch[b][t]; ch[b][t] = a; a += v; }
    tot[t] = a; meta[t] = a;
  }
  __syncthreads();
  if (t == 0) {
    int a = 0, ts = 0;
#pragma unroll
    for (int e = 0; e < 8; ++e) {
      int tiles = (tot[e] + 127) >> 7;
      poff_s[e] = a; tiles_s[e] = tiles;
      meta[16 + e] = a; meta[32 + e] = ts;
      a += tiles << 7; ts += tiles;
    }
    poff_s[8] = a; meta[24] = a; meta[40] = ts;
  }
  __syncthreads();
  // slot assignment: slot = expert base + chunk base + thread offset + running
#pragma unroll
  for (int i = 0; i < 8; ++i) {
    int n = base_tok + i;
    int e0 = te[i].x, e1 = te[i].y;
    int o0 = sm_off[t * 8 + e0]++;
    int s0 = poff_s[e0] + ch[g][e0] + o0;
    int o1 = sm_off[t * 8 + e1]++;
    int s1 = poff_s[e1] + ch[g][e1] + o1;
    rows[s0] = n; rw[s0] = tw[i].x; slot_of[2 * n] = s0;
    rows[s1] = n; rw[s1] = tw[i].y; slot_of[2 * n + 1] = s1;
  }
  // pad fill (dup row 0 with weight 0)
#pragma unroll
  for (int e = 0; e < 8; ++e) {
    int padn = (tiles_s[e] << 7) - tot[e];
    if (t < padn) {
      int s = poff_s[e] + tot[e] + t;
      rows[s] = 0; rw[s] = 0.f;
    }
  }
}

// ================= 3. GEMM1: h = gelu(gather(xbf) @ w1 + b1), h bf16 =================
// Round-0 verified geometry: 128x128, BK=32, 2-buffer async LDS (32KB, 3 blocks/CU).
// NEW: XCD-grouping block swizzle. Dispatch round-robins consecutive blocks over
// 8 XCDs (heuristic), so: xcd = lin&7, and each XCD owns a CONTIGUOUS run of 17
// tiles with all 8 nt-columns of a tile adjacent in time -> shared A-tile (gathered
// xbf rows) is fetched into that XCD's L2 once instead of 8 HBM re-fetches, and an
// expert's B panel (~1MB) stays L2-resident across its tile run. 136 = 8*17 exact.
// Swizzle: chunk (r, c in 0..3) at LDS slot r*4 + (c ^ ((r>>1)&3)) -> 2 lanes/bank (free).
__global__ __launch_bounds__(256) void k_gemm1(
    const unsigned short* __restrict__ xbf, const unsigned short* __restrict__ w1t,
    const float* __restrict__ b1, const int* __restrict__ meta,
    const int* __restrict__ rows, unsigned short* __restrict__ h) {
  int lin = blockIdx.x;
  int xcd = lin & 7, j = lin >> 3;
  int t = xcd * 17 + (j >> 3);           // tile
  int nt = j & 7;                        // output column block
  if (t >= meta[40]) return;
  int e = 0;
#pragma unroll
  for (int i = 1; i < 8; ++i) if (t >= meta[32 + i]) e = i;
  int mt = t - meta[32 + e];
  int row0 = meta[16 + e] + (mt << 7);
  __shared__ __align__(16) unsigned short As[2][4096];
  __shared__ __align__(16) unsigned short Bs[2][4096];
  int tid = threadIdx.x;
  int wave = tid >> 6, lane = tid & 63;
  int wr = wave & 1, wc = wave >> 1;
  f32x4 acc[4][4] = {};   // acc[an][am]
  const unsigned short* bBase = w1t + (size_t)e * HID * DIM + (size_t)(nt * 128) * DIM;

  // K-invariant staging addresses: 512 chunks of 8 elems (128 rows x 4 chunks), 2/thread
  const unsigned short* ga[2]; const unsigned short* gb[2];
#pragma unroll
  for (int jj = 0; jj < 2; ++jj) {
    int s = jj * 256 + tid;
    int r = s >> 2;
    int cg = ((s & 3) ^ ((r >> 1) & 3)) << 3;   // inverse swizzle -> global elem col
    ga[jj] = xbf + (size_t)rows[row0 + r] * DIM + cg;
    gb[jj] = bBase + (size_t)r * DIM + cg;
  }
  int ldst = (wave * 64) * 8;   // wave-uniform LDS elem base (+ lane*16B implicit)

  // prologue: stage tile 0 into buf 0
#pragma unroll
  for (int jj = 0; jj < 2; ++jj) {
    async16(&As[0][jj * 2048 + ldst], ga[jj]);
    async16(&Bs[0][jj * 2048 + ldst], gb[jj]);
  }
  __syncthreads();

  for (int k0 = 0; k0 < DIM; k0 += 32) {
    int cur = (k0 >> 5) & 1, nxt = cur ^ 1;
    if (k0 + 32 < DIM) {
#pragma unroll
      for (int jj = 0; jj < 2; ++jj) {
        async16(&As[nxt][jj * 2048 + ldst], ga[jj] + k0 + 32);
        async16(&Bs[nxt][jj * 2048 + ldst], gb[jj] + k0 + 32);
      }
    }
    {
      int ca = lane >> 4;                  // quad's K-chunk (K=32 = 4 chunks of 8)
      short8 tf[4], wf[4];
#pragma unroll
      for (int am = 0; am < 4; ++am) {
        int ra = wr * 64 + am * 16 + (lane & 15);
        tf[am] = *(const short8*)&As[cur][(ra * 4 + (ca ^ ((ra >> 1) & 3))) * 8];
      }
#pragma unroll
      for (int an = 0; an < 4; ++an) {
        int rb = wc * 64 + an * 16 + (lane & 15);
        wf[an] = *(const short8*)&Bs[cur][(rb * 4 + (ca ^ ((rb >> 1) & 3))) * 8];
      }
#pragma unroll
      for (int an = 0; an < 4; ++an)
#pragma unroll
        for (int am = 0; am < 4; ++am)
          acc[an][am] = __builtin_amdgcn_mfma_f32_16x16x32_bf16(wf[an], tf[am], acc[an][am], 0, 0, 0);
    }
    __syncthreads();   // drains lgkm (cur reads done) + vmcnt (prefetch arrived)
  }
  // epilogue: lane holds token row (lane&15) x 4 consecutive cols (quad*4..+3)
  int ml = lane & 15, q = lane >> 4;
#pragma unroll
  for (int am = 0; am < 4; ++am) {
    int slot_r = row0 + wr * 64 + am * 16 + ml;
    unsigned short* hrow = h + (size_t)slot_r * HID;
#pragma unroll
    for (int an = 0; an < 4; ++an) {
      int colb = nt * 128 + wc * 64 + an * 16 + q * 4;
      float4 bias = *(const float4*)&b1[e * HID + colb];
      f32x4 v = acc[an][am];
      float g0 = gelu_f(v[0] + bias.x);
      float g1 = gelu_f(v[1] + bias.y);
      float g2 = gelu_f(v[2] + bias.z);
      float g3 = gelu_f(v[3] + bias.w);
      uint2 pk;
      pk.x = f2bfu(g0) | (f2bfu(g1) << 16);
      pk.y = f2bfu(g2) | (f2bfu(g3) << 16);
      *(uint2*)(hrow + colb) = pk;
    }
  }
}

// ================= 4. GEMM2: y = (h @ w2 + b2) * weight, y bf16 =================
// Round-0 geometry, K = HID = 1024, BK=32 dbuf. XCD-grouping swizzle: 4 nt-blocks
// of a tile on one XCD -> h A-tile (256KB) fetched once per XCD, not 4x.
__global__ __launch_bounds__(256) void k_gemm2(
    const unsigned short* __restrict__ h, const unsigned short* __restrict__ w2t,
    const float* __restrict__ b2, const int* __restrict__ meta,
    const float* __restrict__ rw, unsigned short* __restrict__ y) {
  int lin = blockIdx.x;
  int xcd = lin & 7, j = lin >> 3;
  int t = xcd * 17 + (j >> 2);
  int nt = j & 3;
  if (t >= meta[40]) return;
  int e = 0;
#pragma unroll
  for (int i = 1; i < 8; ++i) if (t >= meta[32 + i]) e = i;
  int mt = t - meta[32 + e];
  int row0 = meta[16 + e] + (mt << 7);
  __shared__ __align__(16) unsigned short As[2][4096];
  __shared__ __align__(16) unsigned short Bs[2][4096];
  int tid = threadIdx.x;
  int wave = tid >> 6, lane = tid & 63;
  int wr = wave & 1, wc = wave >> 1;
  f32x4 acc[4][4] = {};   // acc[an][am]
  const unsigned short* aBase = h + (size_t)row0 * HID;
  const unsigned short* bBase = w2t + (size_t)e * DIM * HID + (size_t)(nt * 128) * HID;

  const unsigned short* ga[2]; const unsigned short* gb[2];
#pragma unroll
  for (int jj = 0; jj < 2; ++jj) {
    int s = jj * 256 + tid;
    int r = s >> 2;
    int cg = ((s & 3) ^ ((r >> 1) & 3)) << 3;
    ga[jj] = aBase + (size_t)r * HID + cg;
    gb[jj] = bBase + (size_t)r * HID + cg;
  }
  int ldst = (wave * 64) * 8;

#pragma unroll
  for (int jj = 0; jj < 2; ++jj) {
    async16(&As[0][jj * 2048 + ldst], ga[jj]);
    async16(&Bs[0][jj * 2048 + ldst], gb[jj]);
  }
  __syncthreads();

  for (int k0 = 0; k0 < HID; k0 += 32) {
    int cur = (k0 >> 5) & 1, nxt = cur ^ 1;
    if (k0 + 32 < HID) {
#pragma unroll
      for (int jj = 0; jj < 2; ++jj) {
        async16(&As[nxt][jj * 2048 + ldst], ga[jj] + k0 + 32);
        async16(&Bs[nxt][jj * 2048 + ldst], gb[jj] + k0 + 32);
      }
    }
    {
      int ca = lane >> 4;
      short8 tf[4], wf[4];
#pragma unroll
      for (int am = 0; am < 4; ++am) {
        int ra = wr * 64 + am * 16 + (lane & 15);
        tf[am] = *(const short8*)&As[cur][(ra * 4 + (ca ^ ((ra >> 1) & 3))) * 8];
      }
#pragma unroll
      for (int an = 0; an < 4; ++an) {
        int rb = wc * 64 + an * 16 + (lane & 15);
        wf[an] = *(const short8*)&Bs[cur][(rb * 4 + (ca ^ ((rb >> 1) & 3))) * 8];
      }
#pragma unroll
      for (int an = 0; an < 4; ++an)
#pragma unroll
        for (int am = 0; am < 4; ++am)
          acc[an][am] = __builtin_amdgcn_mfma_f32_16x16x32_bf16(wf[an], tf[am], acc[an][am], 0, 0, 0);
    }
    __syncthreads();
  }
  int ml = lane & 15, q = lane >> 4;
#pragma unroll
  for (int am = 0; am < 4; ++am) {
    int slot_r = row0 + wr * 64 + am * 16 + ml;
    float w = rw[slot_r];
    unsigned short* yrow = y + (size_t)slot_r * DIM;
#pragma unroll
    for (int an = 0; an < 4; ++an) {
      int colb = nt * 128 + wc * 64 + an * 16 + q * 4;
      float4 bias = *(const float4*)&b2[e * DIM + colb];
      f32x4 v = acc[an][am];
      uint2 pk;
      pk.x = f2bfu((v[0] + bias.x) * w) | (f2bfu((v[1] + bias.y) * w) << 16);
      pk.y = f2bfu((v[2] + bias.z) * w) | (f2bfu((v[3] + bias.w) * w) << 16);
      *(uint2*)(yrow + colb) = pk;
    }
  }
}

// ================= 5. combine: out[n] = y[slot0] + y[slot1] (bf16 -> fp32) =================
__global__ __launch_bounds__(256) void k_combine(
    const unsigned short* __restrict__ y, const int* __restrict__ slot_of,
    float* __restrict__ out) {
  int t = blockIdx.x * 256 + threadIdx.x;
  int n = t >> 6, c = (t & 63) << 3;
  int s0 = slot_of[2 * n], s1 = slot_of[2 * n + 1];
  uint4 u0 = *(const uint4*)(y + (size_t)s0 * DIM + c);
  uint4 u1 = *(const uint4*)(y + (size_t)s1 * DIM + c);
  float4 o0, o1;
  o0.x = bf2f(u0.x) + bf2f(u1.x); o0.y = bf2f(u0.x >> 16) + bf2f(u1.x >> 16);
  o0.z = bf2f(u0.y) + bf2f(u1.y); o0.w = bf2f(u0.y >> 16) + bf2f(u1.y >> 16);
  o1.x = bf2f(u0.z) + bf2f(u1.z); o1.y = bf2f(u0.z >> 16) + bf2f(u1.z >> 16);
  o1.z = bf2f(u0.w) + bf2f(u1.w); o1.w = bf2f(u0.w >> 16) + bf2f(u1.w >> 16);
  *(float4*)(out + (size_t)n * DIM + c) = o0;
  *(float4*)(out + (size_t)n * DIM + c + 4) = o1;
}

// ================= launch =================
extern "C" void kernel_launch(void* const* d_in, const int* in_sizes, int n_in,
                              void* d_out, int out_size, void* d_ws, size_t ws_size,
                              hipStream_t stream) {
  const float* x  = (const float*)d_in[0];
  const float* gw = (const float*)d_in[1];
  const float* gb = (const float*)d_in[2];
  const float* w1 = (const float*)d_in[3];
  const float* b1 = (const float*)d_in[4];
  const float* w2 = (const float*)d_in[5];
  const float* b2 = (const float*)d_in[6];
  float* out = (float*)d_out;
  char* ws = (char*)d_ws;

  unsigned short* w1t = (unsigned short*)(ws + W1T_OFF);
  unsigned short* w2t = (unsigned short*)(ws + W2T_OFF);
  unsigned short* h   = (unsigned short*)(ws + H_OFF);
  unsigned short* y   = (unsigned short*)(ws + Y_OFF);
  unsigned short* xbf = (unsigned short*)(ws + XBF_OFF);
  int2*   topi    = (int2*)(ws + TOPI_OFF);
  float2* topw    = (float2*)(ws + TOPW_OFF);
  int*    slot_of = (int*)(ws + SLOT_OFF);
  int*    rows    = (int*)(ws + ROWS_OFF);
  float*  rw      = (float*)(ws + RW_OFF);
  int*    meta    = (int*)(ws + CNT_OFF);
  float*  probs   = out + (size_t)N_TOK * DIM;

  k_prep       <<<dim3(4096), dim3(256),  0, stream>>>(w1, w2, w1t, w2t,
                                                       x, gw, gb, probs, topi, topw, xbf);
  k_countassign<<<dim3(1),    dim3(1024), 0, stream>>>(topi, topw, meta, rows, rw, slot_of);
  k_gemm1      <<<dim3(1088), dim3(256),  0, stream>>>(xbf, w1t, b1, meta, rows, h);
  k_gemm2      <<<dim3(544),  dim3(256),  0, stream>>>(h, w2t, b2, meta, rw, y);
  k_combine    <<<dim3(2048), dim3(256),  0, stream>>>(y, slot_of, out);
}